// Round 8
// baseline (183.311 us; speedup 1.0000x reference)
//
#include <hip/hip_runtime.h>
#include <math.h>

#define BB 8
#define HH 16
#define NN 1024
#define TB 256
#define POWN 2          // own points per thread
#define OCH 512         // own points per block
#define SCH 512         // scan points per block (half of NN)
#define GRID (BB * HH * 4)          // 512 blocks: (bh, oh, sh)

// ws layout:
//   floats [0, 262144): partials  part[(bh*2+sh)*NN + i]  (1 MB, all written)
//   byte offset 1 MiB:  uint32 completion counter (zeroed via 4-B memset)
#define WS_PART_FLOATS (BB * HH * 2 * NN)

// ---------------------------------------------------------------------------
// Fused kernel. Chamfer part == R6's proven config exactly:
// pass A only (reflection is an involutive isometry -> both chamfer terms
// equal; sde = 2*mean_i min_j d2). Block (bh, oh, sh): own = reflected pts
// [oh*512,+512), POWN=2/thread, coords pre-scaled by -2; scan = raw samples
// [sh*512,+512) in LDS as float4{x,y,z,sq}; 4-deep unrolled broadcast scan.
// Then last-finishing block (device-scope counter) runs the finalize inline.
// ---------------------------------------------------------------------------
__global__ __launch_bounds__(TB) void fused_kernel(
    const float* __restrict__ y_pred,
    const float* __restrict__ sp,
    float* __restrict__ ws,
    unsigned int* __restrict__ counter,
    float* __restrict__ out)
{
    __shared__ __align__(16) float4 pts[SCH];   // 8 KB
    __shared__ int is_last_s;

    const int blk = blockIdx.x;
    const int bh  = blk >> 2;
    const int oh  = (blk >> 1) & 1;
    const int sh  = blk & 1;
    const int b   = bh >> 4;            // HH = 16
    const int tid = threadIdx.x;

    {
        float pnx = y_pred[bh * 4 + 0];
        float pny = y_pred[bh * 4 + 1];
        float pnz = y_pred[bh * 4 + 2];
        float pd  = y_pred[bh * 4 + 3];
        float inv = 1.0f / sqrtf(pnx * pnx + pny * pny + pnz * pnz);
        pnx *= inv; pny *= inv; pnz *= inv;

        const float* spb = sp + (size_t)b * NN * 3;

        // stage scan half: raw samples with squared norm
        for (int k = tid; k < SCH; k += TB) {
            int j = sh * SCH + k;
            float x = spb[j * 3 + 0], y = spb[j * 3 + 1], z = spb[j * 3 + 2];
            pts[k] = make_float4(x, y, z, x * x + y * y + z * z);
        }

        // own points: reflected, pre-scaled by -2
        float mx[POWN], my[POWN], mz[POWN], osq[POWN];
#pragma unroll
        for (int u = 0; u < POWN; ++u) {
            int i = oh * OCH + u * TB + tid;
            float x = spb[i * 3 + 0], y = spb[i * 3 + 1], z = spb[i * 3 + 2];
            float proj = x * pnx + y * pny + z * pnz + pd;
            x -= 2.0f * proj * pnx;
            y -= 2.0f * proj * pny;
            z -= 2.0f * proj * pnz;
            osq[u] = x * x + y * y + z * z;
            mx[u] = -2.0f * x; my[u] = -2.0f * y; mz[u] = -2.0f * z;
        }
        __syncthreads();

        float m0[POWN], m1[POWN], m2[POWN], m3[POWN];
#pragma unroll
        for (int u = 0; u < POWN; ++u) { m0[u] = 3.4e38f; m1[u] = 3.4e38f; m2[u] = 3.4e38f; m3[u] = 3.4e38f; }

        for (int j = 0; j < SCH; j += 4) {
            float4 qa = pts[j + 0];
            float4 qb = pts[j + 1];
            float4 qc = pts[j + 2];
            float4 qd = pts[j + 3];
#pragma unroll
            for (int u = 0; u < POWN; ++u) {
                m0[u] = fminf(m0[u], fmaf(mx[u], qa.x, fmaf(my[u], qa.y, fmaf(mz[u], qa.z, qa.w))));
                m1[u] = fminf(m1[u], fmaf(mx[u], qb.x, fmaf(my[u], qb.y, fmaf(mz[u], qb.z, qb.w))));
                m2[u] = fminf(m2[u], fmaf(mx[u], qc.x, fmaf(my[u], qc.y, fmaf(mz[u], qc.z, qc.w))));
                m3[u] = fminf(m3[u], fmaf(mx[u], qd.x, fmaf(my[u], qd.y, fmaf(mz[u], qd.z, qd.w))));
            }
        }

        float* wp = ws + ((size_t)(bh * 2 + sh)) * NN + oh * OCH;
#pragma unroll
        for (int u = 0; u < POWN; ++u)
            wp[u * TB + tid] = osq[u] + fminf(fminf(m0[u], m1[u]), fminf(m2[u], m3[u]));
    }

    // ---- completion protocol: release fence + device-scope counter ----
    __syncthreads();                       // all waves' stores issued & drained
    if (tid == 0) {
        __threadfence();                   // release: writes visible device-wide
        unsigned int old = atomicAdd(counter, 1u);
        is_last_s = (old == (unsigned int)(GRID - 1)) ? 1 : 0;
    }
    __syncthreads();
    if (!is_last_s) return;
    __threadfence();                       // acquire: invalidate stale L1/L2

    // =================== finalize (runs on exactly one block) ===============
    __shared__ float sde_s[HH], nx_s[HH], ny_s[HH], nz_s[HH], d_s[HH], conf_s[HH];
    __shared__ float cmacc[3];
    __shared__ int keep_s[HH];

    if (tid < HH) sde_s[tid] = 0.0f;
    if (tid < 3)  cmacc[tid] = 0.0f;
    __syncthreads();

    for (int bb = 0; bb < BB; ++bb) {
        // centroid of batch bb
        const float* spb = sp + (size_t)bb * NN * 3;
        float sx = 0.0f, sy = 0.0f, sz = 0.0f;
        for (int p = tid; p < NN; p += TB) {
            sx += spb[p * 3 + 0];
            sy += spb[p * 3 + 1];
            sz += spb[p * 3 + 2];
        }
        for (int off = 32; off; off >>= 1) {
            sx += __shfl_down(sx, off, 64);
            sy += __shfl_down(sy, off, 64);
            sz += __shfl_down(sz, off, 64);
        }
        if ((tid & 63) == 0) {
            atomicAdd(&cmacc[0], sx);
            atomicAdd(&cmacc[1], sy);
            atomicAdd(&cmacc[2], sz);
        }

        // sde: per h, coalesced float4 min-combine of the 2 scan-half partials
        for (int h = 0; h < HH; ++h) {
            const float4* p0 = (const float4*)(ws + ((size_t)((bb * HH + h) * 2 + 0)) * NN);
            const float4* p1 = (const float4*)(ws + ((size_t)((bb * HH + h) * 2 + 1)) * NN);
            float4 a = p0[tid], c = p1[tid];
            float acc = (fminf(a.x, c.x) + fminf(a.y, c.y)) +
                        (fminf(a.z, c.z) + fminf(a.w, c.w));
            for (int off = 32; off; off >>= 1) acc += __shfl_down(acc, off, 64);
            if ((tid & 63) == 0) atomicAdd(&sde_s[h], acc);
        }
        __syncthreads();

        const float cmx = cmacc[0] / NN, cmy = cmacc[1] / NN, cmz = cmacc[2] / NN;

        if (tid < HH) {
            int h = tid;
            float nx = y_pred[(bb * HH + h) * 4 + 0];
            float ny = y_pred[(bb * HH + h) * 4 + 1];
            float nz = y_pred[(bb * HH + h) * 4 + 2];
            float d  = y_pred[(bb * HH + h) * 4 + 3];
            float inv = 1.0f / sqrtf(nx * nx + ny * ny + nz * nz);
            nx *= inv; ny *= inv; nz *= inv;
            nx_s[h] = nx; ny_s[h] = ny; nz_s[h] = nz; d_s[h] = d;
            sde_s[h] = sde_s[h] * (2.0f / NN);   // both chamfer terms equal
        }
        __syncthreads();

        if (tid < HH) {
            int h = tid;
            float mn = sde_s[0], mx = sde_s[0];
            for (int g = 1; g < HH; ++g) {
                mn = fminf(mn, sde_s[g]);
                mx = fmaxf(mx, sde_s[g]);
            }
            float sde  = sde_s[h];
            float conf = 1.0f - (sde - mn) / fabsf(mx - mn);
            conf_s[h]  = conf;
            bool valid = (sde <= 10.0f);
            bool sup   = false;
            if (valid) {
                for (int g = 0; g < HH; ++g) {
                    if (g == h) continue;
                    float c = nx_s[h] * nx_s[g] + ny_s[h] * ny_s[g] + nz_s[h] * nz_s[g];
                    c = fminf(1.0f, fmaxf(-1.0f, c));
                    float ang = acosf(c) * 57.29577951308232f;
                    bool close = (ang < 30.0f) || (180.0f - ang < 30.0f);
                    if (close && (sde_s[g] <= 10.0f) && (sde >= sde_s[g])) sup = true;
                }
            }
            keep_s[h] = (valid && !sup) ? 1 : 0;
        }
        __syncthreads();

        if (tid < HH) {
            int h = tid;
            // stable descending rank on key = keep ? conf : -inf (argsort(-key))
            float keyh = keep_s[h] ? conf_s[h] : -INFINITY;
            int pos = 0;
            for (int g = 0; g < HH; ++g) {
                float keyg = keep_s[g] ? conf_s[g] : -INFINITY;
                if (keyg > keyh || (keyg == keyh && g < h)) ++pos;
            }
            float nx = nx_s[h], ny = ny_s[h], nz = nz_s[h];
            float t  = nx * cmx + ny * cmy + nz * cmz + d_s[h];
            float px = cmx - t * nx, py = cmy - t * ny, pz = cmz - t * nz;

            float* o = out + (size_t)(bb * HH + pos) * 8;
            if (keep_s[h]) {
                o[0] = nx; o[1] = ny; o[2] = nz;
                o[3] = px; o[4] = py; o[5] = pz;
                o[6] = conf_s[h];
                o[7] = sde_s[h];
            } else {
                for (int c = 0; c < 8; ++c) o[c] = 0.0f;
            }
        }
        __syncthreads();
        // reset per-batch accumulators for next bb
        if (tid < HH) sde_s[tid] = 0.0f;
        if (tid < 3)  cmacc[tid] = 0.0f;
        __syncthreads();
    }
}

extern "C" void kernel_launch(void* const* d_in, const int* in_sizes, int n_in,
                              void* d_out, int out_size, void* d_ws, size_t ws_size,
                              hipStream_t stream) {
    const float* y_pred = (const float*)d_in[0];   // (8,16,4) f32
    const float* sp     = (const float*)d_in[1];   // (8,1024,3) f32
    float* out          = (float*)d_out;           // (8,16,8) f32
    float* ws           = (float*)d_ws;
    unsigned int* cnt   = (unsigned int*)((char*)d_ws + (size_t)WS_PART_FLOATS * sizeof(float));

    hipMemsetAsync(cnt, 0, sizeof(unsigned int), stream);
    fused_kernel<<<dim3(GRID), dim3(TB), 0, stream>>>(y_pred, sp, ws, cnt, out);
}

// Round 9
// 86.937 us; speedup vs baseline: 2.1086x; 2.1086x over previous
//
#include <hip/hip_runtime.h>
#include <math.h>

#define BB 8
#define HH 16
#define NN 1024
#define TB 256
#define POWN 4          // own points per thread -> block owns all 1024
#define SCH 256         // scan points per block (quarter)
#define SHN 4           // scan chunks per bh
#define GRID (BB * HH * SHN)   // 512 blocks

// ws layout:
//   [0, 128*1024) floats: mins[bh*NN + i] — combined via int-punned atomicMin,
//   initialized to 0x7F7F7F7F (3.39e38f) by a 512 KB memset node.
#define WS_MIN_FLOATS (BB * HH * NN)

// ---------------------------------------------------------------------------
// chamfer (pass A only — reflection is an involutive isometry, so both
// chamfer terms are equal: sde = 2*mean_i min_j d2).
// Block (bh, sh): own = ALL 1024 reflected points (POWN=4/thread, coords
// pre-scaled by -2), scan = samples [sh*256,+256) in LDS as float4{x,y,z,sq}.
// One broadcast ds_read_b128 feeds 16 VALU ops -> VALU-bound (~13K LDS cyc/CU
// < 16.4K VALU cyc/SIMD). Chunk results combined with global atomicMin on
// int-punned floats (ordering == float ordering for x>=0; keys are >=0 up to
// ~1e-6 fp noise, far under the 2% threshold).
// ---------------------------------------------------------------------------
__global__ __launch_bounds__(TB) void chamfer_kernel(
    const float* __restrict__ y_pred,
    const float* __restrict__ sp,
    int* __restrict__ ws_min)
{
    __shared__ __align__(16) float4 pts[SCH];   // 4 KB

    const int blk = blockIdx.x;
    const int bh  = blk >> 2;
    const int sh  = blk & 3;
    const int b   = bh >> 4;            // HH = 16
    const int tid = threadIdx.x;

    float pnx = y_pred[bh * 4 + 0];
    float pny = y_pred[bh * 4 + 1];
    float pnz = y_pred[bh * 4 + 2];
    float pd  = y_pred[bh * 4 + 3];
    float inv = 1.0f / sqrtf(pnx * pnx + pny * pny + pnz * pnz);
    pnx *= inv; pny *= inv; pnz *= inv;

    const float* spb = sp + (size_t)b * NN * 3;

    // stage scan chunk: one point per thread
    {
        int j = sh * SCH + tid;
        float x = spb[j * 3 + 0], y = spb[j * 3 + 1], z = spb[j * 3 + 2];
        pts[tid] = make_float4(x, y, z, x * x + y * y + z * z);
    }

    // own points: reflected, pre-scaled by -2
    float mx[POWN], my[POWN], mz[POWN], osq[POWN];
#pragma unroll
    for (int u = 0; u < POWN; ++u) {
        int i = u * TB + tid;
        float x = spb[i * 3 + 0], y = spb[i * 3 + 1], z = spb[i * 3 + 2];
        float proj = x * pnx + y * pny + z * pnz + pd;
        x -= 2.0f * proj * pnx;
        y -= 2.0f * proj * pny;
        z -= 2.0f * proj * pnz;
        osq[u] = x * x + y * y + z * z;
        mx[u] = -2.0f * x; my[u] = -2.0f * y; mz[u] = -2.0f * z;
    }
    __syncthreads();

    float m0[POWN], m1[POWN], m2[POWN], m3[POWN];
#pragma unroll
    for (int u = 0; u < POWN; ++u) { m0[u] = 3.4e38f; m1[u] = 3.4e38f; m2[u] = 3.4e38f; m3[u] = 3.4e38f; }

    for (int j = 0; j < SCH; j += 4) {
        float4 qa = pts[j + 0];
        float4 qb = pts[j + 1];
        float4 qc = pts[j + 2];
        float4 qd = pts[j + 3];
#pragma unroll
        for (int u = 0; u < POWN; ++u) {
            m0[u] = fminf(m0[u], fmaf(mx[u], qa.x, fmaf(my[u], qa.y, fmaf(mz[u], qa.z, qa.w))));
            m1[u] = fminf(m1[u], fmaf(mx[u], qb.x, fmaf(my[u], qb.y, fmaf(mz[u], qb.z, qb.w))));
            m2[u] = fminf(m2[u], fmaf(mx[u], qc.x, fmaf(my[u], qc.y, fmaf(mz[u], qc.z, qc.w))));
            m3[u] = fminf(m3[u], fmaf(mx[u], qd.x, fmaf(my[u], qd.y, fmaf(mz[u], qd.z, qd.w))));
        }
    }

    int* wm = ws_min + (size_t)bh * NN;
#pragma unroll
    for (int u = 0; u < POWN; ++u) {
        float v = osq[u] + fminf(fminf(m0[u], m1[u]), fminf(m2[u], m3[u]));
        atomicMin(&wm[u * TB + tid], __float_as_int(v));
    }
}

// ---------------------------------------------------------------------------
// finalize (per batch, 256 threads): centroid; sde[h] = 2/N * sum_i mins
// (single coalesced float4 pass, no min-combine); conf; angle-NMS; stable
// rank; output write.
// ---------------------------------------------------------------------------
__global__ __launch_bounds__(TB) void finalize_kernel(
    const float* __restrict__ ws_min,
    const float* __restrict__ y_pred,
    const float* __restrict__ sp,
    float* __restrict__ out)
{
    const int b   = blockIdx.x;
    const int tid = threadIdx.x;

    __shared__ float sde_s[HH], nx_s[HH], ny_s[HH], nz_s[HH], d_s[HH], conf_s[HH];
    __shared__ float cmacc[3];
    __shared__ int keep_s[HH];

    if (tid < HH) sde_s[tid] = 0.0f;
    if (tid < 3)  cmacc[tid] = 0.0f;
    __syncthreads();

    // centroid
    const float* spb = sp + (size_t)b * NN * 3;
    float sx = 0.0f, sy = 0.0f, sz = 0.0f;
    for (int p = tid; p < NN; p += TB) {
        sx += spb[p * 3 + 0];
        sy += spb[p * 3 + 1];
        sz += spb[p * 3 + 2];
    }
    for (int off = 32; off; off >>= 1) {
        sx += __shfl_down(sx, off, 64);
        sy += __shfl_down(sy, off, 64);
        sz += __shfl_down(sz, off, 64);
    }
    if ((tid & 63) == 0) {
        atomicAdd(&cmacc[0], sx);
        atomicAdd(&cmacc[1], sy);
        atomicAdd(&cmacc[2], sz);
    }

    // sde: per h, one coalesced float4 load per thread, sum-reduce
    for (int h = 0; h < HH; ++h) {
        const float4* pm = (const float4*)(ws_min + (size_t)(b * HH + h) * NN);
        float4 a = pm[tid];
        float acc = (a.x + a.y) + (a.z + a.w);
        for (int off = 32; off; off >>= 1) acc += __shfl_down(acc, off, 64);
        if ((tid & 63) == 0) atomicAdd(&sde_s[h], acc);
    }
    __syncthreads();

    const float cmx = cmacc[0] / NN, cmy = cmacc[1] / NN, cmz = cmacc[2] / NN;

    if (tid < HH) {
        int h = tid;
        float nx = y_pred[(b * HH + h) * 4 + 0];
        float ny = y_pred[(b * HH + h) * 4 + 1];
        float nz = y_pred[(b * HH + h) * 4 + 2];
        float d  = y_pred[(b * HH + h) * 4 + 3];
        float inv = 1.0f / sqrtf(nx * nx + ny * ny + nz * nz);
        nx *= inv; ny *= inv; nz *= inv;
        nx_s[h] = nx; ny_s[h] = ny; nz_s[h] = nz; d_s[h] = d;
        sde_s[h] = sde_s[h] * (2.0f / NN);     // both chamfer terms equal
    }
    __syncthreads();

    if (tid < HH) {
        int h = tid;
        float mn = sde_s[0], mx = sde_s[0];
        for (int g = 1; g < HH; ++g) {
            mn = fminf(mn, sde_s[g]);
            mx = fmaxf(mx, sde_s[g]);
        }
        float sde  = sde_s[h];
        float conf = 1.0f - (sde - mn) / fabsf(mx - mn);
        conf_s[h]  = conf;
        bool valid = (sde <= 10.0f);
        bool sup   = false;
        if (valid) {
            for (int g = 0; g < HH; ++g) {
                if (g == h) continue;
                float c = nx_s[h] * nx_s[g] + ny_s[h] * ny_s[g] + nz_s[h] * nz_s[g];
                c = fminf(1.0f, fmaxf(-1.0f, c));
                float ang = acosf(c) * 57.29577951308232f;
                bool close = (ang < 30.0f) || (180.0f - ang < 30.0f);
                if (close && (sde_s[g] <= 10.0f) && (sde >= sde_s[g])) sup = true;
            }
        }
        keep_s[h] = (valid && !sup) ? 1 : 0;
    }
    __syncthreads();

    if (tid < HH) {
        int h = tid;
        // stable descending rank on key = keep ? conf : -inf (jnp.argsort(-key))
        float keyh = keep_s[h] ? conf_s[h] : -INFINITY;
        int pos = 0;
        for (int g = 0; g < HH; ++g) {
            float keyg = keep_s[g] ? conf_s[g] : -INFINITY;
            if (keyg > keyh || (keyg == keyh && g < h)) ++pos;
        }
        float nx = nx_s[h], ny = ny_s[h], nz = nz_s[h];
        float t  = nx * cmx + ny * cmy + nz * cmz + d_s[h];
        float px = cmx - t * nx, py = cmy - t * ny, pz = cmz - t * nz;

        float* o = out + (size_t)(b * HH + pos) * 8;
        if (keep_s[h]) {
            o[0] = nx; o[1] = ny; o[2] = nz;
            o[3] = px; o[4] = py; o[5] = pz;
            o[6] = conf_s[h];
            o[7] = sde_s[h];
        } else {
            for (int c = 0; c < 8; ++c) o[c] = 0.0f;
        }
    }
}

extern "C" void kernel_launch(void* const* d_in, const int* in_sizes, int n_in,
                              void* d_out, int out_size, void* d_ws, size_t ws_size,
                              hipStream_t stream) {
    const float* y_pred = (const float*)d_in[0];   // (8,16,4) f32
    const float* sp     = (const float*)d_in[1];   // (8,1024,3) f32
    float* out          = (float*)d_out;           // (8,16,8) f32
    int*   ws_min       = (int*)d_ws;              // 512 KB min array

    // init mins to 0x7F7F7F7F == 3.39e38f (> any real key)
    hipMemsetAsync(ws_min, 0x7F, (size_t)WS_MIN_FLOATS * sizeof(int), stream);
    chamfer_kernel<<<dim3(GRID), dim3(TB), 0, stream>>>(y_pred, sp, ws_min);
    finalize_kernel<<<dim3(BB), dim3(TB), 0, stream>>>((const float*)ws_min, y_pred, sp, out);
}

// Round 10
// 78.744 us; speedup vs baseline: 2.3279x; 1.1040x over previous
//
#include <hip/hip_runtime.h>
#include <math.h>

#define BB 8
#define HH 16
#define NN 1024
#define TB 256
#define POWN 2          // own points per thread
#define OCH 512         // own points per block
#define SCH 512         // scan points per block (half of NN)

// ws layout (floats): partial row-mins
//   part[(bh*2 + sh)*NN + i] = min over scan-half sh of key(i, j)  (+ own_sq)
// 128*2*1024 = 262144 floats = 1 MB. Every slot written exactly once.

// ---------------------------------------------------------------------------
// chamfer: ONLY pass A is computed. By the reflection-isometry identity,
//   sum_j min_i d2[i,j] == sum_i min_j d2[i,j],  so sde = 2*mean_i min_j d2.
// Block (bh, oh, sh): own = reflected points [oh*512, +512) (POWN=2/thread,
// coords pre-scaled by -2), scan = raw samples [sh*512, +512) in LDS as
// float4{x,y,z,sq}. Inner: key = fma(mx,qx, fma(my,qy, fma(mz,qz, q.sq))),
// 4-deep unroll (4 outstanding broadcast ds_read_b128 per iteration).
// Writes per-own-point partials (coalesced), no atomics, no ws init.
// NOTE: POWN=2/SCH=512 is the measured optimum — POWN=4/SCH=256 variants
// (R7/R9) regressed ~9 us despite fewer LDS broadcasts; do not "improve".
// ---------------------------------------------------------------------------
__global__ __launch_bounds__(TB) void chamfer_kernel(
    const float* __restrict__ y_pred,
    const float* __restrict__ sp,
    float* __restrict__ ws)
{
    __shared__ __align__(16) float4 pts[SCH];   // 8 KB

    const int blk = blockIdx.x;
    const int bh  = blk >> 2;
    const int oh  = (blk >> 1) & 1;
    const int sh  = blk & 1;
    const int b   = bh >> 4;            // HH = 16
    const int tid = threadIdx.x;

    float pnx = y_pred[bh * 4 + 0];
    float pny = y_pred[bh * 4 + 1];
    float pnz = y_pred[bh * 4 + 2];
    float pd  = y_pred[bh * 4 + 3];
    float inv = 1.0f / sqrtf(pnx * pnx + pny * pny + pnz * pnz);
    pnx *= inv; pny *= inv; pnz *= inv;

    const float* spb = sp + (size_t)b * NN * 3;

    // stage scan half: raw samples with squared norm
    for (int k = tid; k < SCH; k += TB) {
        int j = sh * SCH + k;
        float x = spb[j * 3 + 0], y = spb[j * 3 + 1], z = spb[j * 3 + 2];
        pts[k] = make_float4(x, y, z, x * x + y * y + z * z);
    }

    // own points: reflected, pre-scaled by -2
    float mx[POWN], my[POWN], mz[POWN], osq[POWN];
#pragma unroll
    for (int u = 0; u < POWN; ++u) {
        int i = oh * OCH + u * TB + tid;
        float x = spb[i * 3 + 0], y = spb[i * 3 + 1], z = spb[i * 3 + 2];
        float proj = x * pnx + y * pny + z * pnz + pd;
        x -= 2.0f * proj * pnx;
        y -= 2.0f * proj * pny;
        z -= 2.0f * proj * pnz;
        osq[u] = x * x + y * y + z * z;
        mx[u] = -2.0f * x; my[u] = -2.0f * y; mz[u] = -2.0f * z;
    }
    __syncthreads();

    float m0[POWN], m1[POWN], m2[POWN], m3[POWN];
#pragma unroll
    for (int u = 0; u < POWN; ++u) { m0[u] = 3.4e38f; m1[u] = 3.4e38f; m2[u] = 3.4e38f; m3[u] = 3.4e38f; }

    for (int j = 0; j < SCH; j += 4) {
        float4 qa = pts[j + 0];
        float4 qb = pts[j + 1];
        float4 qc = pts[j + 2];
        float4 qd = pts[j + 3];
#pragma unroll
        for (int u = 0; u < POWN; ++u) {
            m0[u] = fminf(m0[u], fmaf(mx[u], qa.x, fmaf(my[u], qa.y, fmaf(mz[u], qa.z, qa.w))));
            m1[u] = fminf(m1[u], fmaf(mx[u], qb.x, fmaf(my[u], qb.y, fmaf(mz[u], qb.z, qb.w))));
            m2[u] = fminf(m2[u], fmaf(mx[u], qc.x, fmaf(my[u], qc.y, fmaf(mz[u], qc.z, qc.w))));
            m3[u] = fminf(m3[u], fmaf(mx[u], qd.x, fmaf(my[u], qd.y, fmaf(mz[u], qd.z, qd.w))));
        }
    }

    float* wp = ws + ((size_t)(bh * 2 + sh)) * NN + oh * OCH;
#pragma unroll
    for (int u = 0; u < POWN; ++u)
        wp[u * TB + tid] = osq[u] + fminf(fminf(m0[u], m1[u]), fminf(m2[u], m3[u]));
}

// ---------------------------------------------------------------------------
// finalize (per batch, 256 threads): centroid; sde[h] = 2/N * sum_i
// min(part[h][0][i], part[h][1][i]); conf; angle-NMS; stable rank; write.
// ---------------------------------------------------------------------------
__global__ __launch_bounds__(TB) void finalize_kernel(
    const float* __restrict__ ws,
    const float* __restrict__ y_pred,
    const float* __restrict__ sp,
    float* __restrict__ out)
{
    const int b   = blockIdx.x;
    const int tid = threadIdx.x;

    __shared__ float sde_s[HH], nx_s[HH], ny_s[HH], nz_s[HH], d_s[HH], conf_s[HH];
    __shared__ float cmacc[3];
    __shared__ int keep_s[HH];

    if (tid < HH) sde_s[tid] = 0.0f;
    if (tid < 3)  cmacc[tid] = 0.0f;
    __syncthreads();

    // centroid: 1024 samples over 256 threads
    const float* spb = sp + (size_t)b * NN * 3;
    float sx = 0.0f, sy = 0.0f, sz = 0.0f;
    for (int p = tid; p < NN; p += TB) {
        sx += spb[p * 3 + 0];
        sy += spb[p * 3 + 1];
        sz += spb[p * 3 + 2];
    }
    for (int off = 32; off; off >>= 1) {
        sx += __shfl_down(sx, off, 64);
        sy += __shfl_down(sy, off, 64);
        sz += __shfl_down(sz, off, 64);
    }
    if ((tid & 63) == 0) {
        atomicAdd(&cmacc[0], sx);
        atomicAdd(&cmacc[1], sy);
        atomicAdd(&cmacc[2], sz);
    }

    // sde accumulation: 16 threads per h, each covers 64 i's
    {
        const int h   = tid >> 4;
        const int sub = tid & 15;
        const float* p0 = ws + ((size_t)((b * HH + h) * 2 + 0)) * NN;
        const float* p1 = ws + ((size_t)((b * HH + h) * 2 + 1)) * NN;
        float acc = 0.0f;
        for (int k = 0; k < 64; ++k) {
            int i = sub * 64 + k;
            acc += fminf(p0[i], p1[i]);
        }
        atomicAdd(&sde_s[h], acc);
    }
    __syncthreads();

    const float cmx = cmacc[0] / NN, cmy = cmacc[1] / NN, cmz = cmacc[2] / NN;

    if (tid < HH) {
        int h = tid;
        float nx = y_pred[(b * HH + h) * 4 + 0];
        float ny = y_pred[(b * HH + h) * 4 + 1];
        float nz = y_pred[(b * HH + h) * 4 + 2];
        float d  = y_pred[(b * HH + h) * 4 + 3];
        float inv = 1.0f / sqrtf(nx * nx + ny * ny + nz * nz);
        nx *= inv; ny *= inv; nz *= inv;
        nx_s[h] = nx; ny_s[h] = ny; nz_s[h] = nz; d_s[h] = d;
        sde_s[h] = sde_s[h] * (2.0f / NN);     // both chamfer terms are equal
    }
    __syncthreads();

    if (tid < HH) {
        int h = tid;
        float mn = sde_s[0], mx = sde_s[0];
        for (int g = 1; g < HH; ++g) {
            mn = fminf(mn, sde_s[g]);
            mx = fmaxf(mx, sde_s[g]);
        }
        float sde  = sde_s[h];
        float conf = 1.0f - (sde - mn) / fabsf(mx - mn);
        conf_s[h]  = conf;
        bool valid = (sde <= 10.0f);
        bool sup   = false;
        if (valid) {
            for (int g = 0; g < HH; ++g) {
                if (g == h) continue;
                float c = nx_s[h] * nx_s[g] + ny_s[h] * ny_s[g] + nz_s[h] * nz_s[g];
                c = fminf(1.0f, fmaxf(-1.0f, c));
                float ang = acosf(c) * 57.29577951308232f;
                bool close = (ang < 30.0f) || (180.0f - ang < 30.0f);
                if (close && (sde_s[g] <= 10.0f) && (sde >= sde_s[g])) sup = true;
            }
        }
        keep_s[h] = (valid && !sup) ? 1 : 0;
    }
    __syncthreads();

    if (tid < HH) {
        int h = tid;
        // stable descending rank on key = keep ? conf : -inf (jnp.argsort(-key))
        float keyh = keep_s[h] ? conf_s[h] : -INFINITY;
        int pos = 0;
        for (int g = 0; g < HH; ++g) {
            float keyg = keep_s[g] ? conf_s[g] : -INFINITY;
            if (keyg > keyh || (keyg == keyh && g < h)) ++pos;
        }
        float nx = nx_s[h], ny = ny_s[h], nz = nz_s[h];
        float t  = nx * cmx + ny * cmy + nz * cmz + d_s[h];
        float px = cmx - t * nx, py = cmy - t * ny, pz = cmz - t * nz;

        float* o = out + (size_t)(b * HH + pos) * 8;
        if (keep_s[h]) {
            o[0] = nx; o[1] = ny; o[2] = nz;
            o[3] = px; o[4] = py; o[5] = pz;
            o[6] = conf_s[h];
            o[7] = sde_s[h];
        } else {
            for (int c = 0; c < 8; ++c) o[c] = 0.0f;
        }
    }
}

extern "C" void kernel_launch(void* const* d_in, const int* in_sizes, int n_in,
                              void* d_out, int out_size, void* d_ws, size_t ws_size,
                              hipStream_t stream) {
    const float* y_pred = (const float*)d_in[0];   // (8,16,4) f32
    const float* sp     = (const float*)d_in[1];   // (8,1024,3) f32
    float* out          = (float*)d_out;           // (8,16,8) f32
    float* ws           = (float*)d_ws;            // 1 MB partials, all written

    chamfer_kernel<<<dim3(BB * HH * 4), dim3(TB), 0, stream>>>(y_pred, sp, ws);
    finalize_kernel<<<dim3(BB), dim3(TB), 0, stream>>>(ws, y_pred, sp, out);
}